// Round 2
// baseline (194.936 us; speedup 1.0000x reference)
//
#include <hip/hip_runtime.h>
#include <math.h>

#define E_DIM 4096
#define H_NUM 32
#define D_DIM 128
#define PAST_K 8191
#define K_TOT 8192

typedef float f32x4 __attribute__((ext_vector_type(4)));

// workspace layout (float offsets)
#define WS_QUERY 0                       // 4096
#define WS_KV    4096                    // 256 (key_new 0:128, value_new 128:256)
#define WS_PQ    4608                    // q partials: 128 splits x 4096
#define WS_PKV   (WS_PQ + 128*4096)      // kv partials: 16 splits x 256
#define WS_PA    (WS_PKV + 16*256)       // attn partials: 128 kx x 4096
#define WS_PL    (WS_PA + 128*4096)      // l partials: 128 kx x 4 hy x 8
#define WS_PP    (WS_PL + 4096)          // proj partials: 128 splits x 4096
#define WS_FLAGS (WS_PP + 128*4096)      // int flags: [0,272) qkv, [272,528) proj

#define MAGIC  0x3A91C27D
#define NFLAG1 272
#define NFLAG3 256

// agent-scope (device-coherent, L2-write-through) 8-byte partial store
__device__ inline void st_agent_f2(float* p, float a, float b) {
    union { float f[2]; unsigned long long u; } v;
    v.f[0] = a; v.f[1] = b;
    __hip_atomic_store(reinterpret_cast<unsigned long long*>(p), v.u,
                       __ATOMIC_RELAXED, __HIP_MEMORY_SCOPE_AGENT);
}

__device__ inline void set_flag(int* f) {
    asm volatile("" ::: "memory");   // keep flag store after the barrier-drained partial stores
    __hip_atomic_store(f, MAGIC, __ATOMIC_RELAXED, __HIP_MEMORY_SCOPE_AGENT);
}

__device__ inline void spin_flag(const int* f) {
    while (__hip_atomic_load(f, __ATOMIC_RELAXED, __HIP_MEMORY_SCOPE_AGENT) != MAGIC)
        __builtin_amdgcn_s_sleep(8);
}

// ---------------------------------------------------------------- fused q/kv matvec + reduce (one launch)
// grid: 408 blocks x 512 thr.
//   id <  256: q producer  (strip=id>>7: 2048 cols; by=id&127: 32 rows)
//   id <  272: kv producer (k=id-256: 256 rows x 256 cols)
//   id >= 272: consumer    (c=id-272: 32 outputs; c<128 -> q, else kv)
// Consumers (136) << resident capacity (512 @ 2/CU) -> spin-wait is deadlock-free
// regardless of dispatch order.
__global__ void __launch_bounds__(512, 2)
k_qkv_f(const float* __restrict__ hs,
        const float* __restrict__ q_w,
        const float* __restrict__ kv_w,
        const float* __restrict__ q_b,
        const float* __restrict__ kv_b,
        float* __restrict__ ws, float* __restrict__ out) {
    __shared__ f32x4 sm[576];   // kv: kred[8][64]; consumer: rr[64][8] + rr2[8][8]
    int* flags = reinterpret_cast<int*>(ws + WS_FLAGS);
    const int id = blockIdx.x;
    const int t = threadIdx.x;

    if (id < 256) {              // ---- q producer
        const int strip = id >> 7;
        const int by = id & 127;
        const int e0 = by * 32;
        const int o = strip * 2048 + t * 4;
        float ax = 0.f, ay = 0.f, az = 0.f, aw = 0.f;
#pragma unroll
        for (int i = 0; i < 32; ++i) {
            const float x = hs[e0 + i];
            const float4 w = *reinterpret_cast<const float4*>(q_w + (size_t)(e0 + i) * E_DIM + o);
            ax += x * w.x; ay += x * w.y; az += x * w.z; aw += x * w.w;
        }
        float* p = ws + WS_PQ + (size_t)by * 4096 + o;
        st_agent_f2(p, ax, ay);
        st_agent_f2(p + 2, az, aw);
        __syncthreads();         // drains every wave's vmcnt -> partials device-visible
        if (t == 0) set_flag(&flags[id]);
    } else if (id < 272) {       // ---- kv producer
        const int k = id - 256;
        const int ol = t & 63;
        const int rg = t >> 6;
        const int o = ol * 4;
        float ax = 0.f, ay = 0.f, az = 0.f, aw = 0.f;
#pragma unroll
        for (int i = 0; i < 32; ++i) {
            const int r = k * 256 + rg * 32 + i;
            const float x = hs[r];
            const float4 w = *reinterpret_cast<const float4*>(kv_w + (size_t)r * 256 + o);
            ax += x * w.x; ay += x * w.y; az += x * w.z; aw += x * w.w;
        }
        sm[rg * 64 + ol] = (f32x4){ax, ay, az, aw};
        __syncthreads();
        if (t < 64) {
            f32x4 v = {0.f, 0.f, 0.f, 0.f};
#pragma unroll
            for (int g = 0; g < 8; ++g) v += sm[g * 64 + t];
            float* p = ws + WS_PKV + k * 256 + t * 4;
            st_agent_f2(p, v.x, v.y);
            st_agent_f2(p + 2, v.z, v.w);
        }
        __syncthreads();
        if (t == 0) set_flag(&flags[256 + k]);
    } else {                     // ---- consumer
        const int c = id - 272;
        if (c < 128) {           // q outputs [c*32, c*32+32)
            const int o0 = c * 32;
            const int s = c >> 6;
            if (t < 128) spin_flag(&flags[s * 128 + t]);
            __syncthreads();
            if (t == 0) (void)__hip_atomic_load(&flags[s * 128], __ATOMIC_ACQUIRE,
                                                __HIP_MEMORY_SCOPE_AGENT);  // buffer_inv
            __syncthreads();
            const int ol = t & 7, sg = t >> 3;      // 8 f4-outs x 64 groups(2 splits)
            const int o = o0 + ol * 4;
            f32x4 acc = *reinterpret_cast<const f32x4*>(ws + WS_PQ + (size_t)(2 * sg) * 4096 + o)
                      + *reinterpret_cast<const f32x4*>(ws + WS_PQ + (size_t)(2 * sg + 1) * 4096 + o);
            sm[sg * 8 + ol] = acc;
            __syncthreads();
            if (t < 64) {
                const int sup = t >> 3, l = t & 7;
                f32x4 v = {0.f, 0.f, 0.f, 0.f};
#pragma unroll
                for (int j = 0; j < 8; ++j) v += sm[(sup * 8 + j) * 8 + l];
                sm[512 + sup * 8 + l] = v;
            }
            __syncthreads();
            if (t < 8) {
                f32x4 v = {0.f, 0.f, 0.f, 0.f};
#pragma unroll
                for (int s2 = 0; s2 < 8; ++s2) v += sm[512 + s2 * 8 + t];
                const int oo = o0 + t * 4;
#pragma unroll
                for (int j = 0; j < 4; ++j) ws[WS_QUERY + oo + j] = v[j] + q_b[oo + j];
            }
        } else {                 // kv outputs
            const int o0k = (c - 128) * 32;
            if (t < 16) spin_flag(&flags[256 + t]);
            __syncthreads();
            if (t == 0) (void)__hip_atomic_load(&flags[256], __ATOMIC_ACQUIRE,
                                                __HIP_MEMORY_SCOPE_AGENT);
            __syncthreads();
            if (t < 128) {
                const int ol = t & 7, sg = t >> 3;  // sg < 16
                sm[sg * 8 + ol] = *reinterpret_cast<const f32x4*>(ws + WS_PKV + sg * 256 + o0k + ol * 4);
            }
            __syncthreads();
            if (t < 8) {
                f32x4 v = {0.f, 0.f, 0.f, 0.f};
#pragma unroll
                for (int g = 0; g < 16; ++g) v += sm[g * 8 + t];
                const int i0 = o0k + t * 4;
#pragma unroll
                for (int j = 0; j < 4; ++j) {
                    const float r = v[j] + kv_b[i0 + j];
                    ws[WS_KV + i0 + j] = r;
                    out[4096 + i0 + j] = r;   // key_perm / value_new
                }
            }
        }
    }
}

// ---------------------------------------------------------------- fused attention: scores -> exp -> PV partials
// grid: (128, 4) = 512 blocks, 512 thr. 64 k per bx, 8 heads per by. No atomics.
// Block (0,0) additionally zeroes both flag arrays (L1's for next iteration,
// L3's for this one) -- immune to graph-replay flag staleness.
__global__ void __launch_bounds__(512, 2)
k_attn(const float* __restrict__ past_key,
       const float* __restrict__ past_value,
       const float* __restrict__ mask,
       float* __restrict__ ws) {
    __shared__ float sq[8 * 128];
    __shared__ float sp[8 * 64];
    __shared__ float red[4096];
    const int t = threadIdx.x;
    const int hy = blockIdx.y;
    const int kx = blockIdx.x;
    const int h0 = hy * 8;
    const int k0 = kx * 64;
    const float* __restrict__ kvn = ws + WS_KV;

    if (kx == 0 && hy == 0) {    // zero 528 flags (visible to k_proj_f via kernel-end release)
        int* flags = reinterpret_cast<int*>(ws + WS_FLAGS);
        flags[t] = 0;
        if (t < 16) flags[512 + t] = 0;
    }

    sq[t]       = ws[WS_QUERY + h0 * D_DIM + t];
    sq[t + 512] = ws[WS_QUERY + h0 * D_DIM + t + 512];
    __syncthreads();

    // ---- Phase A: partial scores
    const int kl = t & 63;
    const int team = t >> 6;
    const int d0 = team * 16;
    const int k = k0 + kl;
    const bool tailA = (k == PAST_K);
    const float* kp = tailA ? (kvn + d0) : (past_key + (size_t)d0 * PAST_K + k);
    const size_t kstr = tailA ? 1 : PAST_K;

    float acc[8];
#pragma unroll
    for (int h = 0; h < 8; ++h) acc[h] = 0.f;

#pragma unroll
    for (int i = 0; i < 16; i += 4) {
        const float v0 = kp[0];
        const float v1 = kp[kstr];
        const float v2 = kp[2 * kstr];
        const float v3 = kp[3 * kstr];
        kp += 4 * kstr;
#pragma unroll
        for (int h = 0; h < 8; ++h) {
            const float4 q = *reinterpret_cast<const float4*>(&sq[h * 128 + d0 + i]);
            acc[h] += q.x * v0 + q.y * v1 + q.z * v2 + q.w * v3;
        }
    }
#pragma unroll
    for (int h = 0; h < 8; ++h)
        red[(team * 8 + h) * 64 + kl] = acc[h];
    __syncthreads();

    // ---- parallel softmax: team h handles head h
    {
        const float scale = 0.08838834764831845f;  // 1/sqrt(128)
        const float mk = mask[k];
        float s = 0.f;
#pragma unroll
        for (int tp = 0; tp < 8; ++tp) s += red[(tp * 8 + team) * 64 + kl];
        const float e = __expf(s * scale + mk);
        sp[team * 64 + kl] = e;
        float l = e;
#pragma unroll
        for (int off = 32; off > 0; off >>= 1) l += __shfl_xor(l, off);
        if (kl == 0)
            ws[WS_PL + ((size_t)(kx * 4 + hy)) * 8 + team] = l;
    }
    __syncthreads();

    // ---- Phase B: PV partials
    const int d = t & 127;
    const int kg = t >> 7;
    const int kb = k0 + kg * 16;
    const float* __restrict__ vp = past_value + (size_t)kb * D_DIM + d;
    const float* __restrict__ vlast =
        (kb + 15 == PAST_K) ? (kvn + D_DIM + d) : (vp + 15 * (size_t)D_DIM);

    float b[8];
#pragma unroll
    for (int h = 0; h < 8; ++h) b[h] = 0.f;

#pragma unroll
    for (int kk = 0; kk < 15; ++kk) {
        const float v = vp[(size_t)kk * D_DIM];
#pragma unroll
        for (int h = 0; h < 8; ++h) b[h] += sp[h * 64 + kg * 16 + kk] * v;
    }
    {
        const float v = *vlast;
#pragma unroll
        for (int h = 0; h < 8; ++h) b[h] += sp[h * 64 + kg * 16 + 15] * v;
    }
#pragma unroll
    for (int h = 0; h < 8; ++h)
        red[(kg * 8 + h) * 128 + d] = b[h];
    __syncthreads();

#pragma unroll
    for (int j = 0; j < 2; ++j) {
        const int hh = kg * 2 + j;
        const float s = red[(0 * 8 + hh) * 128 + d] + red[(1 * 8 + hh) * 128 + d] +
                        red[(2 * 8 + hh) * 128 + d] + red[(3 * 8 + hh) * 128 + d];
        ws[WS_PA + (size_t)kx * 4096 + (h0 + hh) * D_DIM + d] = s;
    }
}

// ---------------------------------------------------------------- fused out_proj matvec + reduce (one launch)
// grid: 384 blocks x 512 thr.
//   id <  256: producer (strip=id>>7; by=id&127: rows e0=by*32, one head by>>2)
//   id >= 256: consumer (c=id-256: 32 outputs)
__global__ void __launch_bounds__(512, 2)
k_proj_f(const float* __restrict__ proj_w,
         const float* __restrict__ proj_b,
         float* __restrict__ ws, float* __restrict__ out) {
    __shared__ f32x4 sm[576];
    __shared__ float sred[16 * 32];
    __shared__ float lpart[2];
    __shared__ float sa[32];
    int* flags = reinterpret_cast<int*>(ws + WS_FLAGS);
    const int id = blockIdx.x;
    const int t = threadIdx.x;

    if (id < 256) {              // ---- producer
        const int strip = id >> 7;
        const int by = id & 127;
        const int e0 = by * 32;
        const int h = by >> 2;
        {
            const int el = t & 31, kg = t >> 5;     // 16 groups x 8 kx
            float ps = 0.f;
#pragma unroll
            for (int j = 0; j < 8; ++j)
                ps += ws[WS_PA + (size_t)(kg * 8 + j) * 4096 + e0 + el];
            sred[kg * 32 + el] = ps;
        }
        if (t < 128) {
            float lv = ws[WS_PL + (size_t)t * 32 + (h >> 3) * 8 + (h & 7)];
#pragma unroll
            for (int off = 32; off > 0; off >>= 1) lv += __shfl_xor(lv, off);
            if ((t & 63) == 0) lpart[t >> 6] = lv;
        }
        __syncthreads();
        if (t < 32) {
            float asum = 0.f;
#pragma unroll
            for (int g = 0; g < 16; ++g) asum += sred[g * 32 + t];
            sa[t] = asum / (lpart[0] + lpart[1]);
        }
        __syncthreads();

        const int o = strip * 2048 + t * 4;
        float ax = 0.f, ay = 0.f, az = 0.f, aw = 0.f;
#pragma unroll
        for (int i = 0; i < 32; ++i) {
            const float x = sa[i];  // LDS broadcast
            const float4 w = *reinterpret_cast<const float4*>(proj_w + (size_t)(e0 + i) * E_DIM + o);
            ax += x * w.x; ay += x * w.y; az += x * w.z; aw += x * w.w;
        }
        float* p = ws + WS_PP + (size_t)by * 4096 + o;
        st_agent_f2(p, ax, ay);
        st_agent_f2(p + 2, az, aw);
        __syncthreads();
        if (t == 0) set_flag(&flags[NFLAG1 + id]);
    } else {                     // ---- consumer
        const int c = id - 256;
        const int o0 = c * 32;
        const int s = c >> 6;
        if (t < 128) spin_flag(&flags[NFLAG1 + s * 128 + t]);
        __syncthreads();
        if (t == 0) (void)__hip_atomic_load(&flags[NFLAG1 + s * 128], __ATOMIC_ACQUIRE,
                                            __HIP_MEMORY_SCOPE_AGENT);
        __syncthreads();
        const int ol = t & 7, sg = t >> 3;
        const int o = o0 + ol * 4;
        f32x4 acc = *reinterpret_cast<const f32x4*>(ws + WS_PP + (size_t)(2 * sg) * 4096 + o)
                  + *reinterpret_cast<const f32x4*>(ws + WS_PP + (size_t)(2 * sg + 1) * 4096 + o);
        sm[sg * 8 + ol] = acc;
        __syncthreads();
        if (t < 64) {
            const int sup = t >> 3, l = t & 7;
            f32x4 v = {0.f, 0.f, 0.f, 0.f};
#pragma unroll
            for (int j = 0; j < 8; ++j) v += sm[(sup * 8 + j) * 8 + l];
            sm[512 + sup * 8 + l] = v;
        }
        __syncthreads();
        if (t < 8) {
            f32x4 v = {0.f, 0.f, 0.f, 0.f};
#pragma unroll
            for (int s2 = 0; s2 < 8; ++s2) v += sm[512 + s2 * 8 + t];
            const int oo = o0 + t * 4;
            const f32x4 bb = *reinterpret_cast<const f32x4*>(proj_b + oo);
            *reinterpret_cast<f32x4*>(out + oo) = v + bb;
        }
    }
}

extern "C" void kernel_launch(void* const* d_in, const int* in_sizes, int n_in,
                              void* d_out, int out_size, void* d_ws, size_t ws_size,
                              hipStream_t stream) {
    const float* hs      = (const float*)d_in[0];
    const float* past_k  = (const float*)d_in[1];
    const float* past_v  = (const float*)d_in[2];
    const float* mask    = (const float*)d_in[3];
    const float* q_w     = (const float*)d_in[4];
    const float* q_b     = (const float*)d_in[5];
    const float* kv_w    = (const float*)d_in[6];
    const float* kv_b    = (const float*)d_in[7];
    const float* proj_w  = (const float*)d_in[8];
    const float* proj_b  = (const float*)d_in[9];
    float* out = (float*)d_out;
    float* ws  = (float*)d_ws;

    k_qkv_f <<<dim3(408),    dim3(512), 0, stream>>>(hs, q_w, kv_w, q_b, kv_b, ws, out);
    k_attn  <<<dim3(128, 4), dim3(512), 0, stream>>>(past_k, past_v, mask, ws);
    k_proj_f<<<dim3(384),    dim3(512), 0, stream>>>(proj_w, proj_b, ws, out);
}

// Round 3
// 187.176 us; speedup vs baseline: 1.0415x; 1.0415x over previous
//
#include <hip/hip_runtime.h>
#include <math.h>

#define E_DIM 4096
#define H_NUM 32
#define D_DIM 128
#define PAST_K 8191
#define K_TOT 8192

typedef float f32x4 __attribute__((ext_vector_type(4)));

// workspace layout (float offsets)
#define WS_QUERY 0                       // 4096
#define WS_KV    4096                    // 256 (key_new 0:128, value_new 128:256)
#define WS_PQ    4608                    // qkv partials: 128 splits x 4352
#define WS_PA    (WS_PQ + 128*4352)      // attn partials: 128 kx x 4096
#define WS_PL    (WS_PA + 128*4096)      // l partials: 128 kx x 4 hy x 8
#define WS_PP    (WS_PL + 4096)          // proj partials: 128 splits x 4096

// ---------------------------------------------------------------- q + kv matvec (split-K=128, partial stores)
// grid: (2, 128), 576 thr (9 waves). Waves 0-7: q cols [bx*2048,+2048), 32 rows.
// Wave 8 (bx==0 only): kv 256 outs x 32 rows. Single dispatch round (256 blocks @ 2/CU).
__global__ void __launch_bounds__(576, 2)
k_qkv(const float* __restrict__ hs,
      const float* __restrict__ q_w,
      const float* __restrict__ kv_w,
      float* __restrict__ ws) {
    const int t = threadIdx.x;
    const int e0 = blockIdx.y * 32;
    if (t < 512) {
        const int o = blockIdx.x * 2048 + t * 4;
        float ax = 0.f, ay = 0.f, az = 0.f, aw = 0.f;
#pragma unroll
        for (int i = 0; i < 32; ++i) {
            const int e = e0 + i;
            const float x = hs[e];
            const float4 w = *reinterpret_cast<const float4*>(q_w + (size_t)e * E_DIM + o);
            ax += x * w.x; ay += x * w.y; az += x * w.z; aw += x * w.w;
        }
        *reinterpret_cast<float4*>(ws + WS_PQ + (size_t)blockIdx.y * 4352 + o) =
            make_float4(ax, ay, az, aw);
    } else if (blockIdx.x == 0) {
        const int o = (t - 512) * 4;   // 64 threads x 4 = 256 kv outputs
        float ax = 0.f, ay = 0.f, az = 0.f, aw = 0.f;
#pragma unroll
        for (int i = 0; i < 32; ++i) {
            const int e = e0 + i;
            const float x = hs[e];
            const float4 w = *reinterpret_cast<const float4*>(kv_w + (size_t)e * 256 + o);
            ax += x * w.x; ay += x * w.y; az += x * w.z; aw += x * w.w;
        }
        *reinterpret_cast<float4*>(ws + WS_PQ + (size_t)blockIdx.y * 4352 + 4096 + o) =
            make_float4(ax, ay, az, aw);
    }
}

// ---------------------------------------------------------------- reduce qkv partials (+bias); also emits out[4096:4352]
// grid: 136 blocks x 256 thr. Block: 8 float4-outputs x 32 split-groups(4 splits). float4 loads.
__global__ void __launch_bounds__(256, 4)
k_qkv_reduce(const float* __restrict__ q_b, const float* __restrict__ kv_b,
             float* __restrict__ ws, float* __restrict__ out) {
    __shared__ f32x4 rr[32][8];
    const int t = threadIdx.x;
    const int ol = t & 7;
    const int sg = t >> 3;
    const int o = blockIdx.x * 32 + ol * 4;
    f32x4 acc = {0.f, 0.f, 0.f, 0.f};
#pragma unroll
    for (int s = sg * 4; s < sg * 4 + 4; ++s)
        acc += *reinterpret_cast<const f32x4*>(ws + WS_PQ + (size_t)s * 4352 + o);
    rr[sg][ol] = acc;
    __syncthreads();
    if (t < 8) {
        f32x4 v = {0.f, 0.f, 0.f, 0.f};
#pragma unroll
        for (int g = 0; g < 32; ++g) v += rr[g][t];
        const int oo = blockIdx.x * 32 + t * 4;
        if (oo < 4096) {
#pragma unroll
            for (int j = 0; j < 4; ++j) ws[WS_QUERY + oo + j] = v[j] + q_b[oo + j];
        } else {
            const int i = oo - 4096;
#pragma unroll
            for (int j = 0; j < 4; ++j) {
                const float r = v[j] + kv_b[i + j];
                ws[WS_KV + i + j] = r;
                out[oo + j] = r;   // key_perm / value_new outputs (out[4096:4352])
            }
        }
    }
}

// ---------------------------------------------------------------- fused attention: scores -> exp -> PV partials
// grid: (128, 4) = 512 blocks, 512 thr. 64 k per bx, 8 heads per by. No atomics.
// Phase A: 64 k-lanes x 8 d-teams(16 d); softmax parallel: team h owns head h.
// Phase B: 128 d-lanes x 4 kg(16 k); final sum split across all threads (2 heads each).
__global__ void __launch_bounds__(512, 2)
k_attn(const float* __restrict__ past_key,
       const float* __restrict__ past_value,
       const float* __restrict__ mask,
       float* __restrict__ ws) {
    __shared__ float sq[8 * 128];     // q tile (8 heads x 128 d), 4 KB
    __shared__ float sp[8 * 64];      // unnormalized probs, 2 KB
    __shared__ float red[4096];       // 16 KB (A: [8 teams][8 h][64 k]; B: [4 kg][8 h][128 d])
    const int t = threadIdx.x;
    const int hy = blockIdx.y;
    const int kx = blockIdx.x;
    const int h0 = hy * 8;
    const int k0 = kx * 64;
    const float* __restrict__ kvn = ws + WS_KV;

    sq[t]       = ws[WS_QUERY + h0 * D_DIM + t];
    sq[t + 512] = ws[WS_QUERY + h0 * D_DIM + t + 512];
    __syncthreads();

    // ---- Phase A: partial scores
    const int kl = t & 63;
    const int team = t >> 6;          // == wave id, wave-uniform
    const int d0 = team * 16;
    const int k = k0 + kl;
    const bool tailA = (k == PAST_K);
    const float* kp = tailA ? (kvn + d0) : (past_key + (size_t)d0 * PAST_K + k);
    const size_t kstr = tailA ? 1 : PAST_K;

    float acc[8];
#pragma unroll
    for (int h = 0; h < 8; ++h) acc[h] = 0.f;

#pragma unroll
    for (int i = 0; i < 16; i += 4) {
        const float v0 = kp[0];
        const float v1 = kp[kstr];
        const float v2 = kp[2 * kstr];
        const float v3 = kp[3 * kstr];
        kp += 4 * kstr;
#pragma unroll
        for (int h = 0; h < 8; ++h) {
            const float4 q = *reinterpret_cast<const float4*>(&sq[h * 128 + d0 + i]);
            acc[h] += q.x * v0 + q.y * v1 + q.z * v2 + q.w * v3;
        }
    }
#pragma unroll
    for (int h = 0; h < 8; ++h)
        red[(team * 8 + h) * 64 + kl] = acc[h];
    __syncthreads();

    // ---- parallel softmax: team h handles head h (all 8 waves active)
    {
        const float scale = 0.08838834764831845f;  // 1/sqrt(128)
        const float mk = mask[k];
        float s = 0.f;
#pragma unroll
        for (int tp = 0; tp < 8; ++tp) s += red[(tp * 8 + team) * 64 + kl];
        const float e = __expf(s * scale + mk);
        sp[team * 64 + kl] = e;
        float l = e;
#pragma unroll
        for (int off = 32; off > 0; off >>= 1) l += __shfl_xor(l, off);
        if (kl == 0)
            ws[WS_PL + ((size_t)(kx * 4 + hy)) * 8 + team] = l;
    }
    __syncthreads();   // sp ready; red free for Phase B

    // ---- Phase B: PV partials
    const int d = t & 127;
    const int kg = t >> 7;            // wave-uniform
    const int kb = k0 + kg * 16;
    const float* __restrict__ vp = past_value + (size_t)kb * D_DIM + d;
    const float* __restrict__ vlast =
        (kb + 15 == PAST_K) ? (kvn + D_DIM + d) : (vp + 15 * (size_t)D_DIM);

    float b[8];
#pragma unroll
    for (int h = 0; h < 8; ++h) b[h] = 0.f;

#pragma unroll
    for (int kk = 0; kk < 15; ++kk) {
        const float v = vp[(size_t)kk * D_DIM];
#pragma unroll
        for (int h = 0; h < 8; ++h) b[h] += sp[h * 64 + kg * 16 + kk] * v;
    }
    {
        const float v = *vlast;
#pragma unroll
        for (int h = 0; h < 8; ++h) b[h] += sp[h * 64 + kg * 16 + 15] * v;
    }
#pragma unroll
    for (int h = 0; h < 8; ++h)
        red[(kg * 8 + h) * 128 + d] = b[h];
    __syncthreads();

    // final cross-kg sum, all 512 threads: each handles 2 heads at its d
#pragma unroll
    for (int j = 0; j < 2; ++j) {
        const int hh = kg * 2 + j;
        const float s = red[(0 * 8 + hh) * 128 + d] + red[(1 * 8 + hh) * 128 + d] +
                        red[(2 * 8 + hh) * 128 + d] + red[(3 * 8 + hh) * 128 + d];
        ws[WS_PA + (size_t)kx * 4096 + (h0 + hh) * D_DIM + d] = s;  // coalesced
    }
}

// ---------------------------------------------------------------- out_proj matvec (split-K=128); fused attn/l reduction
// grid: (2, 128), 512 thr. Rows e0 = by*32 (all within head h = by>>2).
__global__ void __launch_bounds__(512, 2)
k_proj(const float* __restrict__ proj_w,
       float* __restrict__ ws) {
    __shared__ float sred[16 * 32];   // [kg16][el32], 2 KB
    __shared__ float lpart[2];
    __shared__ float sa[32];          // normalized attn row chunk
    const int t = threadIdx.x;
    const int by = blockIdx.y;
    const int e0 = by * 32;
    const int h  = by >> 2;           // global head of these rows

    // attn[e0..e0+32) = sum over 128 kx partials (16 groups x 8 kx)
    {
        const int el = t & 31;
        const int kg = t >> 5;
        float ps = 0.f;
#pragma unroll
        for (int j = 0; j < 8; ++j)
            ps += ws[WS_PA + (size_t)(kg * 8 + j) * 4096 + e0 + el];
        sred[kg * 32 + el] = ps;
    }
    // l[h] = sum over 128 kx
    if (t < 128) {
        float lv = ws[WS_PL + (size_t)t * 32 + (h >> 3) * 8 + (h & 7)];
#pragma unroll
        for (int off = 32; off > 0; off >>= 1) lv += __shfl_xor(lv, off);
        if ((t & 63) == 0) lpart[t >> 6] = lv;
    }
    __syncthreads();
    if (t < 32) {
        float asum = 0.f;
#pragma unroll
        for (int g = 0; g < 16; ++g) asum += sred[g * 32 + t];
        sa[t] = asum / (lpart[0] + lpart[1]);
    }
    __syncthreads();

    const int o = blockIdx.x * 2048 + t * 4;
    float ax = 0.f, ay = 0.f, az = 0.f, aw = 0.f;
#pragma unroll
    for (int i = 0; i < 32; ++i) {
        const float x = sa[i];  // LDS broadcast
        const float4 w = *reinterpret_cast<const float4*>(proj_w + (size_t)(e0 + i) * E_DIM + o);
        ax += x * w.x; ay += x * w.y; az += x * w.z; aw += x * w.w;
    }
    *reinterpret_cast<float4*>(ws + WS_PP + (size_t)by * 4096 + o) =
        make_float4(ax, ay, az, aw);
}

// ---------------------------------------------------------------- reduce proj partials (+bias) -> d_out
// grid: 128 blocks x 256 thr. Block: 8 float4-outputs x 32 split-groups(4 splits). float4 loads.
__global__ void __launch_bounds__(256, 4)
k_proj_reduce(const float* __restrict__ proj_b,
              float* __restrict__ ws, float* __restrict__ out) {
    __shared__ f32x4 rr[32][8];
    const int t = threadIdx.x;
    const int ol = t & 7;
    const int sg = t >> 3;
    const int o = blockIdx.x * 32 + ol * 4;
    f32x4 acc = {0.f, 0.f, 0.f, 0.f};
#pragma unroll
    for (int s = sg * 4; s < sg * 4 + 4; ++s)
        acc += *reinterpret_cast<const f32x4*>(ws + WS_PP + (size_t)s * 4096 + o);
    rr[sg][ol] = acc;
    __syncthreads();
    if (t < 8) {
        f32x4 v = {0.f, 0.f, 0.f, 0.f};
#pragma unroll
        for (int g = 0; g < 32; ++g) v += rr[g][t];
        const int oo = blockIdx.x * 32 + t * 4;
        const f32x4 bb = *reinterpret_cast<const f32x4*>(proj_b + oo);
        *reinterpret_cast<f32x4*>(out + oo) = v + bb;
    }
}

extern "C" void kernel_launch(void* const* d_in, const int* in_sizes, int n_in,
                              void* d_out, int out_size, void* d_ws, size_t ws_size,
                              hipStream_t stream) {
    const float* hs      = (const float*)d_in[0];
    const float* past_k  = (const float*)d_in[1];
    const float* past_v  = (const float*)d_in[2];
    const float* mask    = (const float*)d_in[3];
    const float* q_w     = (const float*)d_in[4];
    const float* q_b     = (const float*)d_in[5];
    const float* kv_w    = (const float*)d_in[6];
    const float* kv_b    = (const float*)d_in[7];
    const float* proj_w  = (const float*)d_in[8];
    const float* proj_b  = (const float*)d_in[9];
    float* out = (float*)d_out;
    float* ws  = (float*)d_ws;

    k_qkv        <<<dim3(2, 128), dim3(576), 0, stream>>>(hs, q_w, kv_w, ws);
    k_qkv_reduce <<<dim3(136),    dim3(256), 0, stream>>>(q_b, kv_b, ws, out);
    k_attn       <<<dim3(128, 4), dim3(512), 0, stream>>>(past_k, past_v, mask, ws);
    k_proj       <<<dim3(2, 128), dim3(512), 0, stream>>>(proj_w, ws);
    k_proj_reduce<<<dim3(128),    dim3(256), 0, stream>>>(proj_b, ws, out);
}